// Round 12
// baseline (83.410 us; speedup 1.0000x reference)
//
#include <hip/hip_runtime.h>
#include <hip/hip_bf16.h>
#include <stdint.h>

typedef unsigned long long u64;
typedef float f32x2 __attribute__((ext_vector_type(2)));

#define N 8192
#define K 30
#define NWAVE 2                 // waves per block; both serve the SAME row pair
#define R 2                     // rows per block
#define CAP 320                 // 5 slots * 64 lanes per (wave,row)
#define FLUSH_AT 192            // flush when cnt > 192 (influx <= 128/iter -> <= 320)
#define HALF 2048               // f32x2 elements per wave's half-stream

// ws layout: gx[8192] @0 | gy @32768 | gz @65536 | gw @98304 | list @131072 | ctr @163840

// CDNA packed-f32 (VOP3P): pk_mul/pk_add/pk_fma exist on gfx950; pk_max does NOT.
static __device__ __forceinline__ f32x2 pk_mul(f32x2 a, f32x2 b) {
  f32x2 d; asm("v_pk_mul_f32 %0, %1, %2" : "=v"(d) : "v"(a), "v"(b)); return d;
}
static __device__ __forceinline__ f32x2 pk_add(f32x2 a, f32x2 b) {
  f32x2 d; asm("v_pk_add_f32 %0, %1, %2" : "=v"(d) : "v"(a), "v"(b)); return d;
}
static __device__ __forceinline__ f32x2 pk_fma(f32x2 a, f32x2 b, f32x2 c) {
  f32x2 d; asm("v_pk_fma_f32 %0, %1, %2, %3" : "=v"(d) : "v"(a), "v"(b), "v"(c)); return d;
}
static __device__ __forceinline__ f32x2 clamp0(f32x2 a) {   // exact, = jnp.maximum(d2,0)
  f32x2 d; d.x = fmaxf(a.x, 0.0f); d.y = fmaxf(a.y, 0.0f); return d;
}

__global__ void zero_kernel(int* __restrict__ ctr) {
  if (threadIdx.x < 2) ctr[threadIdx.x] = 0;
}

// ---------------- prep: centroid + sq + validity (SoA), compact row list ----------
// _rn intrinsics: no FMA contraction, bit-match np f32.
__global__ __launch_bounds__(256) void prep_kernel(const float* __restrict__ X,
                                                   const int* __restrict__ C,
                                                   float* __restrict__ gx,
                                                   float* __restrict__ gy,
                                                   float* __restrict__ gz,
                                                   float* __restrict__ gw,
                                                   int* __restrict__ list,
                                                   int* __restrict__ ctr) {
  int i = blockIdx.x * 256 + threadIdx.x;
  if (i >= N) return;
  const float4* xp = (const float4*)(X + (size_t)i * 12);
  float4 f0 = xp[0], f1 = xp[1], f2 = xp[2];
  float mx = __fmul_rn(__fadd_rn(__fadd_rn(__fadd_rn(f0.x, f0.w), f1.z), f2.y), 0.25f);
  float my = __fmul_rn(__fadd_rn(__fadd_rn(__fadd_rn(f0.y, f1.x), f1.w), f2.z), 0.25f);
  float mz = __fmul_rn(__fadd_rn(__fadd_rn(__fadd_rn(f0.z, f1.y), f2.x), f2.w), 0.25f);
  float sq = __fadd_rn(__fadd_rn(__fmul_rn(mx, mx), __fmul_rn(my, my)), __fmul_rn(mz, mz));
  bool valid = (C[i] > 0);
  gx[i] = mx; gy[i] = my; gz[i] = mz;
  gw[i] = valid ? sq : __builtin_inff();
  if (valid) { int p = atomicAdd(&ctr[0], 1); list[p] = i; }
  else       { int p = atomicAdd(&ctr[1], 1); list[N - 1 - p] = i; }
}

// ---------------- bitonic helpers (validated; used once per wave at the end) ------
static __device__ __forceinline__ u64 sort64(u64 v, int lane) {
#pragma unroll
  for (int kk = 2; kk <= 64; kk <<= 1) {
#pragma unroll
    for (int j = kk >> 1; j > 0; j >>= 1) {
      u64 o = __shfl_xor(v, j);
      bool lower = (lane & j) == 0;
      bool asc = (lane & kk) == 0;
      u64 mn = v < o ? v : o;
      u64 mx = v < o ? o : v;
      v = (lower == asc) ? mn : mx;
    }
  }
  return v;
}
static __device__ __forceinline__ u64 merge64(u64 L, u64 v, int lane) {
  u64 vr = __shfl(v, 63 - lane);
  u64 m = L < vr ? L : vr;
#pragma unroll
  for (int j = 32; j > 0; j >>= 1) {
    u64 o = __shfl_xor(m, j);
    bool lower = (lane & j) == 0;
    u64 mn = m < o ? m : o;
    u64 mx = m < o ? o : m;
    m = lower ? mn : mx;
  }
  return m;
}

// -------- radix flush: theta via 16-round bit search, purge; publish shared theta --
// buf entries: (clamped_d2_bits<<32)|idx. theta = granule upper bound >= true 30th.
__device__ __forceinline__ void radix_flush(float& th, unsigned& cnt, u64* bufp,
                                            unsigned* thsh, int lane, u64 lmlt) {
  u64 e0 = (unsigned)(lane)       < cnt ? bufp[lane]       : ~0ull;
  u64 e1 = (unsigned)(lane + 64)  < cnt ? bufp[lane + 64]  : ~0ull;
  u64 e2 = (unsigned)(lane + 128) < cnt ? bufp[lane + 128] : ~0ull;
  u64 e3 = (unsigned)(lane + 192) < cnt ? bufp[lane + 192] : ~0ull;
  u64 e4 = (unsigned)(lane + 256) < cnt ? bufp[lane + 256] : ~0ull;
  unsigned h0 = (unsigned)(e0 >> 32), h1 = (unsigned)(e1 >> 32);
  unsigned h2 = (unsigned)(e2 >> 32), h3 = (unsigned)(e3 >> 32);
  unsigned h4 = (unsigned)(e4 >> 32);

  unsigned piv = 0;
#pragma unroll
  for (int b = 15; b >= 0; --b) {
    unsigned cand = piv + (0x10000u << b);
    int c = __popcll(__ballot(h0 < cand)) + __popcll(__ballot(h1 < cand)) +
            __popcll(__ballot(h2 < cand)) + __popcll(__ballot(h3 < cand)) +
            __popcll(__ballot(h4 < cand));
    if (c < K) piv = cand;           // invariant: count(< piv) < K
  }
  if (piv < 0xFFFF0000u)             // guard: needs >=30 entries to tighten
    th = fminf(th, __uint_as_float(piv + 0x10000u));
  if (thsh && lane == 0) atomicMin(thsh, __float_as_uint(th));

  const unsigned thb = __float_as_uint(th);
  unsigned total = 0;
#define PURGE_SLOT(E, H)                                                      \
  { u64 mk = __ballot((H) < thb);                                             \
    if (mk) {                                                                 \
      unsigned pos = total + (unsigned)__popcll(mk & lmlt);                   \
      if ((H) < thb) bufp[pos] = (E);                                         \
      total += (unsigned)__popcll(mk); } }
  PURGE_SLOT(e0, h0)
  PURGE_SLOT(e1, h1)
  PURGE_SLOT(e2, h2)
  PURGE_SLOT(e3, h3)
  PURGE_SLOT(e4, h4)
#undef PURGE_SLOT
  cnt = total;
}

// -------- final: tighten+purge, then ONE exact bitonic pass over survivors --------
__device__ __forceinline__ u64 finalize_row(float& th, unsigned& cnt, u64* bufp,
                                            int lane, u64 lmlt) {
  radix_flush(th, cnt, bufp, nullptr, lane, lmlt);
  u64 L = ~0ull;
  for (unsigned base = 0; base < cnt; base += 64) {
    u64 v = ~0ull;
    if (base + (unsigned)lane < cnt) {
      u64 raw = bufp[base + lane];
      float d2c = __uint_as_float((unsigned)(raw >> 32));
      float D = sqrtf(__fadd_rn(d2c, 1e-6f));            // exact ref formula
      v = ((u64)__float_as_uint(D) << 32) | (raw & 0xFFFFFFFFull);
    }
    v = sort64(v, lane);
    L = merge64(L, v, lane);
  }
  return L;
}

#define PACK(V, J) (((u64)__float_as_uint(V) << 32) | (unsigned)(J))
#define PROCESS(BUF, CNT, MASK, D2V, JJ)                                       \
  if (MASK) {                                                                  \
    unsigned pos = CNT + (unsigned)__popcll((MASK) & lmlt);                    \
    if (((MASK) >> lane) & 1ull) (BUF)[pos] = PACK(D2V, JJ);                   \
    CNT += (unsigned)__popcll(MASK);                                           \
  }

__device__ __forceinline__ void write_row(int r, bool act, u64 L, int lane,
                                          __hip_bfloat16* __restrict__ out) {
  if (lane >= K) return;
  const int o = r * K + lane;
  if (act) {
    out[o] = __float2bfloat16((float)(unsigned)(L & 0xFFFFFFFFull));
    out[N * K + o] = __float2bfloat16(__uint_as_float((unsigned)(L >> 32)));
    out[2 * N * K + o] = __float2bfloat16(1.0f);
  } else {
    out[o] = __float2bfloat16((float)lane);
    ((unsigned short*)out)[N * K + o] = 0x7F7Fu;   // finite bf16-max vs expected inf
    out[2 * N * K + o] = __float2bfloat16(0.0f);
  }
}

// -- main: 2 waves per row-pair (half-stream each), radix flush, shared theta, ----
// -- final cross-wave exact merge.                                               --
__global__ __launch_bounds__(128) void knn_kernel(const float* __restrict__ gx,
                                                  const float* __restrict__ gy,
                                                  const float* __restrict__ gz,
                                                  const float* __restrict__ gw,
                                                  const int* __restrict__ list,
                                                  const int* __restrict__ ctr,
                                                  __hip_bfloat16* __restrict__ out) {
  __shared__ u64 bufS[NWAVE][R][CAP];
  __shared__ u64 mrg[NWAVE][R][64];
  __shared__ unsigned thSh[R];

  const int lane = threadIdx.x & 63;
  const int w = threadIdx.x >> 6;
  const u64 lmlt = (1ull << lane) - 1ull;
  const int nValid = ctr[0];
  const int pos0 = blockIdx.x * R;
  const int r0 = list[pos0];
  const int r1 = list[pos0 + 1];
  const bool a0 = pos0 < nValid;           // block-uniform
  const bool a1 = pos0 + 1 < nValid;

  if (!a0) {                               // both rows invalid: write + leave
    if (w == 0) write_row(r0, false, 0, lane, out);
    else        write_row(r1, false, 0, lane, out);
    return;
  }

  if (threadIdx.x < R) thSh[threadIdx.x] = 0x7F800000u;   // +inf bits
  __syncthreads();
  volatile unsigned* vth = thSh;

  const float q0x = gx[r0], q0y = gy[r0], q0z = gz[r0], q0w = gw[r0];
  const float q1x = gx[r1], q1y = gy[r1], q1z = gz[r1], q1w = gw[r1];
  const f32x2 q0x2 = {q0x, q0x}, q0y2 = {q0y, q0y}, q0z2 = {q0z, q0z}, q0w2 = {q0w, q0w};
  const f32x2 q1x2 = {q1x, q1x}, q1y2 = {q1y, q1y}, q1z2 = {q1z, q1z}, q1w2 = {q1w, q1w};
  const f32x2 neg1 = {-1.0f, -1.0f};

  float th0 = __builtin_inff();
  float th1 = a1 ? __builtin_inff() : -__builtin_inff();  // inactive row1 never accepts
  unsigned cnt0 = 0, cnt1 = 0;
  u64* b0 = &bufS[w][0][0];
  u64* b1 = &bufS[w][1][0];

  const f32x2* bx = (const f32x2*)gx;
  const f32x2* by = (const f32x2*)gy;
  const f32x2* bz = (const f32x2*)gz;
  const f32x2* bw = (const f32x2*)gw;

  int idx = w * HALF + lane;               // f32x2 index in this wave's half
  f32x2 px = bx[idx], py = by[idx], pz = bz[idx], pw = bw[idx];

#pragma unroll 2
  for (int it = 0; it < HALF / 64; ++it) {
    const int nidx = (it < HALF / 64 - 1) ? idx + 64 : idx;   // depth-1 prefetch
    f32x2 nx = bx[nidx], ny = by[nidx], nz = bz[nidx], nw = bw[nidx];

    // partner's published theta (volatile LDS read; min of two valid bounds is valid)
    th0 = fminf(th0, __uint_as_float(vth[0]));
    th1 = fminf(th1, __uint_as_float(vth[1]));

    // exact np f32 rounding: dot=(qx*px+qy*py)+qz*pz; 2*dot==dot+dot (exact);
    // t-u via fma(u,-1,t) == fsub_rn; clamp fmax(d2,0) exact.
    f32x2 dot0 = pk_add(pk_add(pk_mul(q0x2, px), pk_mul(q0y2, py)), pk_mul(q0z2, pz));
    f32x2 d20 = clamp0(pk_fma(pk_add(dot0, dot0), neg1, pk_add(q0w2, pw)));
    f32x2 dot1 = pk_add(pk_add(pk_mul(q1x2, px), pk_mul(q1y2, py)), pk_mul(q1z2, pz));
    f32x2 d21 = clamp0(pk_fma(pk_add(dot1, dot1), neg1, pk_add(q1w2, pw)));
    u64 me0 = __ballot(d20.x <= th0);
    u64 mo0 = __ballot(d20.y <= th0);
    u64 me1 = __ballot(d21.x <= th1);
    u64 mo1 = __ballot(d21.y <= th1);
    if (me0 | mo0 | me1 | mo1) {
      const int jb = 2 * idx;              // global candidate index (even slot)
      if (me0 | mo0) {
        PROCESS(b0, cnt0, me0, d20.x, jb)
        PROCESS(b0, cnt0, mo0, d20.y, jb + 1)
        if (cnt0 > FLUSH_AT) radix_flush(th0, cnt0, b0, &thSh[0], lane, lmlt);
      }
      if (me1 | mo1) {
        PROCESS(b1, cnt1, me1, d21.x, jb)
        PROCESS(b1, cnt1, mo1, d21.y, jb + 1)
        if (cnt1 > FLUSH_AT) radix_flush(th1, cnt1, b1, &thSh[1], lane, lmlt);
      }
    }
    px = nx; py = ny; pz = nz; pw = nw;
    idx = nidx;
  }

  u64 L0 = finalize_row(th0, cnt0, b0, lane, lmlt);
  u64 L1 = a1 ? finalize_row(th1, cnt1, b1, lane, lmlt) : ~0ull;

  // ---- cross-wave combine: each wave has exact top-64 of its half, per row ----
  mrg[w][0][lane] = L0;
  mrg[w][1][lane] = L1;
  __syncthreads();
  if (w == 0) {
    u64 other = mrg[1][0][lane];
    write_row(r0, true, merge64(L0, other, lane), lane, out);
  } else {
    u64 other = mrg[0][1][lane];
    write_row(r1, a1, merge64(L1, other, lane), lane, out);
  }
}

extern "C" void kernel_launch(void* const* d_in, const int* in_sizes, int n_in,
                              void* d_out, int out_size, void* d_ws, size_t ws_size,
                              hipStream_t stream) {
  const float* X = (const float*)d_in[0];
  const int* C = (const int*)d_in[1];
  float* gx = (float*)d_ws;
  float* gy = (float*)((char*)d_ws + 32768);
  float* gz = (float*)((char*)d_ws + 65536);
  float* gw = (float*)((char*)d_ws + 98304);
  int* list = (int*)((char*)d_ws + 131072);
  int* ctr = (int*)((char*)d_ws + 163840);
  __hip_bfloat16* out = (__hip_bfloat16*)d_out;

  zero_kernel<<<1, 64, 0, stream>>>(ctr);
  prep_kernel<<<N / 256, 256, 0, stream>>>(X, C, gx, gy, gz, gw, list, ctr);
  knn_kernel<<<N / R, 128, 0, stream>>>(gx, gy, gz, gw, list, ctr, out);
}

// Round 13
// 73.532 us; speedup vs baseline: 1.1343x; 1.1343x over previous
//
#include <hip/hip_runtime.h>
#include <hip/hip_bf16.h>
#include <stdint.h>

typedef unsigned long long u64;
typedef float f32x2 __attribute__((ext_vector_type(2)));

#define N 8192
#define K 30
#define NWAVE 4                 // waves per block (256 threads); 1 row per wave
#define CAP 448                 // 7 slots * 64 lanes
#define FLUSH_AT 192            // flush when cnt > 192 (influx <= 256/iter -> <= 448)
#define NITER 32                // 8192 cands / 256 per iter

// ws layout: gx[8192] @0 | gy @32768 | gz @65536 | gw @98304 | list @131072 | ctr @163840

// CDNA packed-f32 (VOP3P): pk_mul/pk_add/pk_fma exist on gfx950; pk_max does NOT.
static __device__ __forceinline__ f32x2 pk_mul(f32x2 a, f32x2 b) {
  f32x2 d; asm("v_pk_mul_f32 %0, %1, %2" : "=v"(d) : "v"(a), "v"(b)); return d;
}
static __device__ __forceinline__ f32x2 pk_add(f32x2 a, f32x2 b) {
  f32x2 d; asm("v_pk_add_f32 %0, %1, %2" : "=v"(d) : "v"(a), "v"(b)); return d;
}
static __device__ __forceinline__ f32x2 pk_fma(f32x2 a, f32x2 b, f32x2 c) {
  f32x2 d; asm("v_pk_fma_f32 %0, %1, %2, %3" : "=v"(d) : "v"(a), "v"(b), "v"(c)); return d;
}
static __device__ __forceinline__ f32x2 clamp0(f32x2 a) {   // exact, = jnp.maximum(d2,0)
  f32x2 d; d.x = fmaxf(a.x, 0.0f); d.y = fmaxf(a.y, 0.0f); return d;
}

__global__ void zero_kernel(int* __restrict__ ctr) {
  if (threadIdx.x < 2) ctr[threadIdx.x] = 0;
}

// ---------------- prep: centroid + sq + validity (SoA), compact row list ----------
// _rn intrinsics: no FMA contraction, bit-match np f32.
__global__ __launch_bounds__(256) void prep_kernel(const float* __restrict__ X,
                                                   const int* __restrict__ C,
                                                   float* __restrict__ gx,
                                                   float* __restrict__ gy,
                                                   float* __restrict__ gz,
                                                   float* __restrict__ gw,
                                                   int* __restrict__ list,
                                                   int* __restrict__ ctr) {
  int i = blockIdx.x * 256 + threadIdx.x;
  if (i >= N) return;
  const float4* xp = (const float4*)(X + (size_t)i * 12);
  float4 f0 = xp[0], f1 = xp[1], f2 = xp[2];
  float mx = __fmul_rn(__fadd_rn(__fadd_rn(__fadd_rn(f0.x, f0.w), f1.z), f2.y), 0.25f);
  float my = __fmul_rn(__fadd_rn(__fadd_rn(__fadd_rn(f0.y, f1.x), f1.w), f2.z), 0.25f);
  float mz = __fmul_rn(__fadd_rn(__fadd_rn(__fadd_rn(f0.z, f1.y), f2.x), f2.w), 0.25f);
  float sq = __fadd_rn(__fadd_rn(__fmul_rn(mx, mx), __fmul_rn(my, my)), __fmul_rn(mz, mz));
  bool valid = (C[i] > 0);
  gx[i] = mx; gy[i] = my; gz[i] = mz;
  gw[i] = valid ? sq : __builtin_inff();
  if (valid) { int p = atomicAdd(&ctr[0], 1); list[p] = i; }
  else       { int p = atomicAdd(&ctr[1], 1); list[N - 1 - p] = i; }
}

// ---------------- bitonic helpers (validated; final phase only) ----------------
static __device__ __forceinline__ u64 sort64(u64 v, int lane) {
#pragma unroll
  for (int kk = 2; kk <= 64; kk <<= 1) {
#pragma unroll
    for (int j = kk >> 1; j > 0; j >>= 1) {
      u64 o = __shfl_xor(v, j);
      bool lower = (lane & j) == 0;
      bool asc = (lane & kk) == 0;
      u64 mn = v < o ? v : o;
      u64 mx = v < o ? o : v;
      v = (lower == asc) ? mn : mx;
    }
  }
  return v;
}
static __device__ __forceinline__ u64 merge64(u64 L, u64 v, int lane) {
  u64 vr = __shfl(v, 63 - lane);
  u64 m = L < vr ? L : vr;
#pragma unroll
  for (int j = 32; j > 0; j >>= 1) {
    u64 o = __shfl_xor(m, j);
    bool lower = (lane & j) == 0;
    u64 mn = m < o ? m : o;
    u64 mx = m < o ? o : m;
    m = lower ? mn : mx;
  }
  return m;
}

// -------- radix flush: theta via 16-round bit search (ballots only), purge --------
// buf entries: (clamped_d2_bits<<32)|idx. theta = granule upper bound >= true 30th
// of all processed so far (superset-safe); purge keeps entries < theta.
__device__ __forceinline__ void radix_flush(float& th, unsigned& cnt, u64* bufp,
                                            int lane, u64 lmlt) {
  u64 e[7];
  unsigned h[7];
#pragma unroll
  for (int s = 0; s < 7; ++s) {
    e[s] = (unsigned)(lane + 64 * s) < cnt ? bufp[lane + 64 * s] : ~0ull;
    h[s] = (unsigned)(e[s] >> 32);
  }
  unsigned piv = 0;
#pragma unroll
  for (int b = 15; b >= 0; --b) {
    unsigned cand = piv + (0x10000u << b);
    int c = 0;
#pragma unroll
    for (int s = 0; s < 7; ++s) c += __popcll(__ballot(h[s] < cand));
    if (c < K) piv = cand;           // invariant: count(< piv) < K
  }
  if (piv < 0xFFFF0000u)             // tighten only with >=30 entries below granule
    th = fminf(th, __uint_as_float(piv + 0x10000u));

  const unsigned thb = __float_as_uint(th);
  unsigned total = 0;
#pragma unroll
  for (int s = 0; s < 7; ++s) {
    u64 mk = __ballot(h[s] < thb);
    if (mk) {
      unsigned pos = total + (unsigned)__popcll(mk & lmlt);
      if (h[s] < thb) bufp[pos] = e[s];
      total += (unsigned)__popcll(mk);
    }
  }
  cnt = total;
}

// -------- final: tighten+purge, then ONE exact bitonic pass over survivors --------
__device__ __forceinline__ u64 finalize_row(float& th, unsigned& cnt, u64* bufp,
                                            int lane, u64 lmlt) {
  radix_flush(th, cnt, bufp, lane, lmlt);
  u64 L = ~0ull;
  for (unsigned base = 0; base < cnt; base += 64) {
    u64 v = ~0ull;
    if (base + (unsigned)lane < cnt) {
      u64 raw = bufp[base + lane];
      float d2c = __uint_as_float((unsigned)(raw >> 32));
      float D = sqrtf(__fadd_rn(d2c, 1e-6f));            // exact ref formula
      v = ((u64)__float_as_uint(D) << 32) | (raw & 0xFFFFFFFFull);
    }
    v = sort64(v, lane);
    L = merge64(L, v, lane);
  }
  return L;
}

#define PACK(V, J) (((u64)__float_as_uint(V) << 32) | (unsigned)(J))
#define PROCESS(BUF, CNT, MASK, D2V, JJ)                                       \
  if (MASK) {                                                                  \
    unsigned pos = CNT + (unsigned)__popcll((MASK) & lmlt);                    \
    if (((MASK) >> lane) & 1ull) (BUF)[pos] = PACK(D2V, JJ);                   \
    CNT += (unsigned)__popcll(MASK);                                           \
  }

__device__ __forceinline__ void write_row(int r, bool act, u64 L, int lane,
                                          __hip_bfloat16* __restrict__ out) {
  if (lane >= K) return;
  const int o = r * K + lane;
  if (act) {
    out[o] = __float2bfloat16((float)(unsigned)(L & 0xFFFFFFFFull));
    out[N * K + o] = __float2bfloat16(__uint_as_float((unsigned)(L >> 32)));
    out[2 * N * K + o] = __float2bfloat16(1.0f);
  } else {
    out[o] = __float2bfloat16((float)lane);
    ((unsigned short*)out)[N * K + o] = 0x7F7Fu;   // finite bf16-max vs expected inf
    out[2 * N * K + o] = __float2bfloat16(0.0f);
  }
}

// -- main: ONE row per wave (8192 waves, 100% nominal residency), full-table L2 ----
// -- stream, 4 cands/lane/iter, radix-select flush, exact final sort.             --
__global__ __launch_bounds__(256) void knn_kernel(const float* __restrict__ gx,
                                                  const float* __restrict__ gy,
                                                  const float* __restrict__ gz,
                                                  const float* __restrict__ gw,
                                                  const int* __restrict__ list,
                                                  const int* __restrict__ ctr,
                                                  __hip_bfloat16* __restrict__ out) {
  __shared__ u64 bufS[NWAVE][CAP];

  const int lane = threadIdx.x & 63;
  const int w = threadIdx.x >> 6;
  const u64 lmlt = (1ull << lane) - 1ull;
  const int nValid = ctr[0];
  const int pos = blockIdx.x * NWAVE + w;
  const int r = list[pos];
  const bool act = pos < nValid;

  if (!act) {                // inactive wave: write defaults + leave (no barriers)
    write_row(r, false, 0, lane, out);
    return;
  }

  const float qx = gx[r], qy = gy[r], qz = gz[r], qw = gw[r];
  const f32x2 qx2 = {qx, qx}, qy2 = {qy, qy}, qz2 = {qz, qz}, qw2 = {qw, qw};
  const f32x2 neg1 = {-1.0f, -1.0f};

  float th = __builtin_inff();
  unsigned cnt = 0;
  u64* bp = &bufS[w][0];

  const f32x2* bx = (const f32x2*)gx;
  const f32x2* by = (const f32x2*)gy;
  const f32x2* bz = (const f32x2*)gz;
  const f32x2* bw = (const f32x2*)gw;

  int base = 0;              // f32x2 base index for this iteration (A at base, B at +64)
  f32x2 aX = bx[lane], aY = by[lane], aZ = bz[lane], aW = bw[lane];
  f32x2 bX = bx[64 + lane], bY = by[64 + lane], bZ = bz[64 + lane], bW = bw[64 + lane];

#pragma unroll 2
  for (int it = 0; it < NITER; ++it) {
    const int nbase = (it < NITER - 1) ? base + 128 : base;   // depth-1 prefetch
    f32x2 naX = bx[nbase + lane], naY = by[nbase + lane];
    f32x2 naZ = bz[nbase + lane], naW = bw[nbase + lane];
    f32x2 nbX = bx[nbase + 64 + lane], nbY = by[nbase + 64 + lane];
    f32x2 nbZ = bz[nbase + 64 + lane], nbW = bw[nbase + 64 + lane];

    // exact np f32 rounding: dot=(qx*px+qy*py)+qz*pz; 2*dot==dot+dot (exact);
    // t-u via fma(u,-1,t) == fsub_rn; clamp fmax(d2,0) exact.
    f32x2 dotA = pk_add(pk_add(pk_mul(qx2, aX), pk_mul(qy2, aY)), pk_mul(qz2, aZ));
    f32x2 dA = clamp0(pk_fma(pk_add(dotA, dotA), neg1, pk_add(qw2, aW)));
    f32x2 dotB = pk_add(pk_add(pk_mul(qx2, bX), pk_mul(qy2, bY)), pk_mul(qz2, bZ));
    f32x2 dB = clamp0(pk_fma(pk_add(dotB, dotB), neg1, pk_add(qw2, bW)));

    bool pA0 = dA.x <= th, pA1 = dA.y <= th, pB0 = dB.x <= th, pB1 = dB.y <= th;
    u64 mA0 = __ballot(pA0), mA1 = __ballot(pA1);
    u64 mB0 = __ballot(pB0), mB1 = __ballot(pB1);
    if (mA0 | mA1 | mB0 | mB1) {
      const unsigned jA = (unsigned)(2 * (base + lane));      // even candidate index
      const unsigned jB = jA + 128;
      PROCESS(bp, cnt, mA0, dA.x, jA)
      PROCESS(bp, cnt, mA1, dA.y, jA + 1)
      PROCESS(bp, cnt, mB0, dB.x, jB)
      PROCESS(bp, cnt, mB1, dB.y, jB + 1)
      if (cnt > FLUSH_AT) radix_flush(th, cnt, bp, lane, lmlt);
    }

    aX = naX; aY = naY; aZ = naZ; aW = naW;
    bX = nbX; bY = nbY; bZ = nbZ; bW = nbW;
    base = nbase;
  }

  u64 L = finalize_row(th, cnt, bp, lane, lmlt);
  write_row(r, true, L, lane, out);
}

extern "C" void kernel_launch(void* const* d_in, const int* in_sizes, int n_in,
                              void* d_out, int out_size, void* d_ws, size_t ws_size,
                              hipStream_t stream) {
  const float* X = (const float*)d_in[0];
  const int* C = (const int*)d_in[1];
  float* gx = (float*)d_ws;
  float* gy = (float*)((char*)d_ws + 32768);
  float* gz = (float*)((char*)d_ws + 65536);
  float* gw = (float*)((char*)d_ws + 98304);
  int* list = (int*)((char*)d_ws + 131072);
  int* ctr = (int*)((char*)d_ws + 163840);
  __hip_bfloat16* out = (__hip_bfloat16*)d_out;

  zero_kernel<<<1, 64, 0, stream>>>(ctr);
  prep_kernel<<<N / 256, 256, 0, stream>>>(X, C, gx, gy, gz, gw, list, ctr);
  knn_kernel<<<N / NWAVE, 256, 0, stream>>>(gx, gy, gz, gw, list, ctr, out);
}

// Round 14
// 66.314 us; speedup vs baseline: 1.2578x; 1.1088x over previous
//
#include <hip/hip_runtime.h>
#include <hip/hip_bf16.h>
#include <stdint.h>

typedef unsigned long long u64;
typedef float f32x2 __attribute__((ext_vector_type(2)));

#define N 8192
#define K 30
#define NWAVE 4                 // waves per block (256 threads); 1 row per wave
#define CAP 576                 // 9 slots * 64 lanes
#define NSLOT 9
#define FLUSH_AT 320            // flush when cnt > 320 (influx <= 256/iter -> <= 576)

// ws layout: gx[8192] @0 | gy @32768 | gz @65536 | gw @98304 | gid @131072 | ctr @163840
// gx..gw are validity-COMPACTED: [0,nValid) valid rows, [nValid,N) w=+inf.
// gid[p] = original node index of compact position p.

static __device__ __forceinline__ f32x2 pk_mul(f32x2 a, f32x2 b) {
  f32x2 d; asm("v_pk_mul_f32 %0, %1, %2" : "=v"(d) : "v"(a), "v"(b)); return d;
}
static __device__ __forceinline__ f32x2 pk_add(f32x2 a, f32x2 b) {
  f32x2 d; asm("v_pk_add_f32 %0, %1, %2" : "=v"(d) : "v"(a), "v"(b)); return d;
}
static __device__ __forceinline__ f32x2 pk_fma(f32x2 a, f32x2 b, f32x2 c) {
  f32x2 d; asm("v_pk_fma_f32 %0, %1, %2, %3" : "=v"(d) : "v"(a), "v"(b), "v"(c)); return d;
}
static __device__ __forceinline__ f32x2 clamp0(f32x2 a) {   // exact, = jnp.maximum(d2,0)
  f32x2 d; d.x = fmaxf(a.x, 0.0f); d.y = fmaxf(a.y, 0.0f); return d;
}

__global__ void zero_kernel(int* __restrict__ ctr) {
  if (threadIdx.x < 2) ctr[threadIdx.x] = 0;
}

// ---------------- prep: centroid + sq + validity, COMPACTED SoA ----------------
// _rn intrinsics: no FMA contraction, bit-match np f32.
__global__ __launch_bounds__(256) void prep_kernel(const float* __restrict__ X,
                                                   const int* __restrict__ C,
                                                   float* __restrict__ gx,
                                                   float* __restrict__ gy,
                                                   float* __restrict__ gz,
                                                   float* __restrict__ gw,
                                                   int* __restrict__ gid,
                                                   int* __restrict__ ctr) {
  int i = blockIdx.x * 256 + threadIdx.x;
  if (i >= N) return;
  const float4* xp = (const float4*)(X + (size_t)i * 12);
  float4 f0 = xp[0], f1 = xp[1], f2 = xp[2];
  float mx = __fmul_rn(__fadd_rn(__fadd_rn(__fadd_rn(f0.x, f0.w), f1.z), f2.y), 0.25f);
  float my = __fmul_rn(__fadd_rn(__fadd_rn(__fadd_rn(f0.y, f1.x), f1.w), f2.z), 0.25f);
  float mz = __fmul_rn(__fadd_rn(__fadd_rn(__fadd_rn(f0.z, f1.y), f2.x), f2.w), 0.25f);
  float sq = __fadd_rn(__fadd_rn(__fmul_rn(mx, mx), __fmul_rn(my, my)), __fmul_rn(mz, mz));
  bool valid = (C[i] > 0);
  int p;
  if (valid) p = atomicAdd(&ctr[0], 1);
  else       p = N - 1 - atomicAdd(&ctr[1], 1);
  gx[p] = mx; gy[p] = my; gz[p] = mz;
  gw[p] = valid ? sq : __builtin_inff();
  gid[p] = i;
}

// ---------------- bitonic helpers (validated; final phase only) ----------------
static __device__ __forceinline__ u64 sort64(u64 v, int lane) {
#pragma unroll
  for (int kk = 2; kk <= 64; kk <<= 1) {
#pragma unroll
    for (int j = kk >> 1; j > 0; j >>= 1) {
      u64 o = __shfl_xor(v, j);
      bool lower = (lane & j) == 0;
      bool asc = (lane & kk) == 0;
      u64 mn = v < o ? v : o;
      u64 mx = v < o ? o : v;
      v = (lower == asc) ? mn : mx;
    }
  }
  return v;
}
static __device__ __forceinline__ u64 merge64(u64 L, u64 v, int lane) {
  u64 vr = __shfl(v, 63 - lane);
  u64 m = L < vr ? L : vr;
#pragma unroll
  for (int j = 32; j > 0; j >>= 1) {
    u64 o = __shfl_xor(m, j);
    bool lower = (lane & j) == 0;
    u64 mn = m < o ? m : o;
    u64 mx = m < o ? o : m;
    m = lower ? mn : mx;
  }
  return m;
}

// -------- radix flush: theta via 16-round bit search (ballots only), purge --------
// buf entries: (clamped_d2_bits<<32)|compact_idx. theta = granule upper bound >=
// true 30th of all processed so far (superset-safe); purge keeps entries < theta.
__device__ __forceinline__ void radix_flush(float& th, unsigned& cnt, u64* bufp,
                                            int lane, u64 lmlt) {
  u64 e[NSLOT];
  unsigned h[NSLOT];
#pragma unroll
  for (int s = 0; s < NSLOT; ++s) {
    e[s] = (unsigned)(lane + 64 * s) < cnt ? bufp[lane + 64 * s] : ~0ull;
    h[s] = (unsigned)(e[s] >> 32);
  }
  unsigned piv = 0;
#pragma unroll
  for (int b = 15; b >= 0; --b) {
    unsigned cand = piv + (0x10000u << b);
    int c = 0;
#pragma unroll
    for (int s = 0; s < NSLOT; ++s) c += __popcll(__ballot(h[s] < cand));
    if (c < K) piv = cand;           // invariant: count(< piv) < K
  }
  if (piv < 0xFFFF0000u)             // tighten only with >=30 entries below granule
    th = fminf(th, __uint_as_float(piv + 0x10000u));

  const unsigned thb = __float_as_uint(th);
  unsigned total = 0;
#pragma unroll
  for (int s = 0; s < NSLOT; ++s) {
    u64 mk = __ballot(h[s] < thb);
    if (mk) {
      unsigned pos = total + (unsigned)__popcll(mk & lmlt);
      if (h[s] < thb) bufp[pos] = e[s];
      total += (unsigned)__popcll(mk);
    }
  }
  cnt = total;
}

// -------- final: tighten+purge, gather ORIGINAL indices, one exact bitonic pass ---
// Sort key: (exact D bits << 32) | original_index -> reference order + tie-breaks.
__device__ __forceinline__ u64 finalize_row(float& th, unsigned& cnt, u64* bufp,
                                            const int* __restrict__ gid,
                                            int lane, u64 lmlt) {
  radix_flush(th, cnt, bufp, lane, lmlt);
  u64 L = ~0ull;
  for (unsigned base = 0; base < cnt; base += 64) {
    u64 v = ~0ull;
    if (base + (unsigned)lane < cnt) {
      u64 raw = bufp[base + lane];
      float d2c = __uint_as_float((unsigned)(raw >> 32));
      float D = sqrtf(__fadd_rn(d2c, 1e-6f));            // exact ref formula
      unsigned jo = (unsigned)gid[(unsigned)(raw & 0xFFFFFFFFull)];
      v = ((u64)__float_as_uint(D) << 32) | jo;
    }
    v = sort64(v, lane);
    L = merge64(L, v, lane);
  }
  return L;
}

#define PACK(V, J) (((u64)__float_as_uint(V) << 32) | (unsigned)(J))
#define PROCESS(BUF, CNT, MASK, D2V, JJ)                                       \
  if (MASK) {                                                                  \
    unsigned pos = CNT + (unsigned)__popcll((MASK) & lmlt);                    \
    if (((MASK) >> lane) & 1ull) (BUF)[pos] = PACK(D2V, JJ);                   \
    CNT += (unsigned)__popcll(MASK);                                           \
  }

__device__ __forceinline__ void write_row(int r, bool act, u64 L, int lane,
                                          __hip_bfloat16* __restrict__ out) {
  if (lane >= K) return;
  const int o = r * K + lane;
  if (act) {
    out[o] = __float2bfloat16((float)(unsigned)(L & 0xFFFFFFFFull));
    out[N * K + o] = __float2bfloat16(__uint_as_float((unsigned)(L >> 32)));
    out[2 * N * K + o] = __float2bfloat16(1.0f);
  } else {
    out[o] = __float2bfloat16((float)lane);
    ((unsigned short*)out)[N * K + o] = 0x7F7Fu;   // finite bf16-max vs expected inf
    out[2 * N * K + o] = __float2bfloat16(0.0f);
  }
}

// -- main: 1 row/wave over the COMPACTED table (ceil(nValid/256) iters), theta- ----
// -- prime, radix flush, exact final sort on (D, original index).                 --
__global__ __launch_bounds__(256) void knn_kernel(const float* __restrict__ gx,
                                                  const float* __restrict__ gy,
                                                  const float* __restrict__ gz,
                                                  const float* __restrict__ gw,
                                                  const int* __restrict__ gid,
                                                  const int* __restrict__ ctr,
                                                  __hip_bfloat16* __restrict__ out) {
  __shared__ u64 bufS[NWAVE][CAP];

  const int lane = threadIdx.x & 63;
  const int w = threadIdx.x >> 6;
  const u64 lmlt = (1ull << lane) - 1ull;
  const int nValid = ctr[0];
  const int pos = blockIdx.x * NWAVE + w;
  const int rout = gid[pos];               // original row index for output
  const bool act = pos < nValid;

  if (!act) {                // inactive wave: write defaults + leave (no barriers)
    write_row(rout, false, 0, lane, out);
    return;
  }

  const float qx = gx[pos], qy = gy[pos], qz = gz[pos], qw = gw[pos];
  const f32x2 qx2 = {qx, qx}, qy2 = {qy, qy}, qz2 = {qz, qz}, qw2 = {qw, qw};
  const f32x2 neg1 = {-1.0f, -1.0f};

  float th = __builtin_inff();
  unsigned cnt = 0;
  u64* bp = &bufS[w][0];

  const f32x2* bx = (const f32x2*)gx;
  const f32x2* by = (const f32x2*)gy;
  const f32x2* bz = (const f32x2*)gz;
  const f32x2* bw = (const f32x2*)gw;

  const int niter = (nValid + 255) >> 8;   // 256 candidates per iteration
  int base = 0;                            // f32x2 base (A at base, B at base+64)
  f32x2 aX = bx[lane], aY = by[lane], aZ = bz[lane], aW = bw[lane];
  f32x2 bX = bx[64 + lane], bY = by[64 + lane], bZ = bz[64 + lane], bW = bw[64 + lane];

#pragma unroll 2
  for (int it = 0; it < niter; ++it) {
    const int nbase = (it < niter - 1) ? base + 128 : base;   // depth-1 prefetch
    f32x2 naX = bx[nbase + lane], naY = by[nbase + lane];
    f32x2 naZ = bz[nbase + lane], naW = bw[nbase + lane];
    f32x2 nbX = bx[nbase + 64 + lane], nbY = by[nbase + 64 + lane];
    f32x2 nbZ = bz[nbase + 64 + lane], nbW = bw[nbase + 64 + lane];

    // exact np f32 rounding: dot=(qx*px+qy*py)+qz*pz; 2*dot==dot+dot (exact);
    // t-u via fma(u,-1,t) == fsub_rn; clamp fmax(d2,0) exact.
    f32x2 dotA = pk_add(pk_add(pk_mul(qx2, aX), pk_mul(qy2, aY)), pk_mul(qz2, aZ));
    f32x2 dA = clamp0(pk_fma(pk_add(dotA, dotA), neg1, pk_add(qw2, aW)));
    f32x2 dotB = pk_add(pk_add(pk_mul(qx2, bX), pk_mul(qy2, bY)), pk_mul(qz2, bZ));
    f32x2 dB = clamp0(pk_fma(pk_add(dotB, dotB), neg1, pk_add(qw2, bW)));

    if (it == 0 && nValid >= 256) {
      // theta-prime: max over lanes of per-lane min-of-4 — >=64 candidates are
      // <= this bound, so theta >= true 30th (exact math, no margin needed).
      float l = fminf(fminf(dA.x, dA.y), fminf(dB.x, dB.y));
#pragma unroll
      for (int d = 32; d; d >>= 1) l = fmaxf(l, __shfl_xor(l, d));
      th = l;
    }

    bool pA0 = dA.x <= th, pA1 = dA.y <= th, pB0 = dB.x <= th, pB1 = dB.y <= th;
    u64 mA0 = __ballot(pA0), mA1 = __ballot(pA1);
    u64 mB0 = __ballot(pB0), mB1 = __ballot(pB1);
    if (mA0 | mA1 | mB0 | mB1) {
      const unsigned jA = (unsigned)(2 * (base + lane));      // compact even index
      const unsigned jB = jA + 128;
      PROCESS(bp, cnt, mA0, dA.x, jA)
      PROCESS(bp, cnt, mA1, dA.y, jA + 1)
      PROCESS(bp, cnt, mB0, dB.x, jB)
      PROCESS(bp, cnt, mB1, dB.y, jB + 1)
      if (cnt > FLUSH_AT) radix_flush(th, cnt, bp, lane, lmlt);
    }

    aX = naX; aY = naY; aZ = naZ; aW = naW;
    bX = nbX; bY = nbY; bZ = nbZ; bW = nbW;
    base = nbase;
  }

  u64 L = finalize_row(th, cnt, bp, gid, lane, lmlt);
  write_row(rout, true, L, lane, out);
}

extern "C" void kernel_launch(void* const* d_in, const int* in_sizes, int n_in,
                              void* d_out, int out_size, void* d_ws, size_t ws_size,
                              hipStream_t stream) {
  const float* X = (const float*)d_in[0];
  const int* C = (const int*)d_in[1];
  float* gx = (float*)d_ws;
  float* gy = (float*)((char*)d_ws + 32768);
  float* gz = (float*)((char*)d_ws + 65536);
  float* gw = (float*)((char*)d_ws + 98304);
  int* gid = (int*)((char*)d_ws + 131072);
  int* ctr = (int*)((char*)d_ws + 163840);
  __hip_bfloat16* out = (__hip_bfloat16*)d_out;

  zero_kernel<<<1, 64, 0, stream>>>(ctr);
  prep_kernel<<<N / 256, 256, 0, stream>>>(X, C, gx, gy, gz, gw, gid, ctr);
  knn_kernel<<<N / NWAVE, 256, 0, stream>>>(gx, gy, gz, gw, gid, ctr, out);
}